// Round 4
// baseline (749.228 us; speedup 1.0000x reference)
//
#include <hip/hip_runtime.h>

#define NN 100000
#define EE 1600000
#define FF 128
#define SS 256
#define CC 32
#define KG 384     // gates GEMM K = F + S
#define NCOL 1024  // gates GEMM N = 4 gates * S

typedef __attribute__((ext_vector_type(8))) short v8s;
typedef __attribute__((ext_vector_type(8))) unsigned short u8s;
typedef __attribute__((ext_vector_type(4))) float v4f;

__device__ __forceinline__ void gload_lds16(const void* g, void* l) {
  __builtin_amdgcn_global_load_lds(
      (const __attribute__((address_space(1))) void*)g,
      (__attribute__((address_space(3))) void*)l, 16, 0, 0);
}

__device__ __forceinline__ unsigned short f2bf(float f) {
  unsigned int u = __float_as_uint(f);
  u += 0x7FFF + ((u >> 16) & 1);  // RNE
  return (unsigned short)(u >> 16);
}
__device__ __forceinline__ float bf2f(unsigned short u) {
  return __uint_as_float(((unsigned int)u) << 16);
}
__device__ __forceinline__ float sigmoidf_(float x) { return 1.0f / (1.0f + __expf(-x)); }
__device__ __forceinline__ float tanhf_(float x) {
  float ax = fabsf(x);
  float e = __expf(2.0f * ax);
  float t = 1.0f - 2.0f / (e + 1.0f);
  return copysignf(t, x);
}

// ---------------- degree / norm + edge histogram ----------------
__global__ __launch_bounds__(256) void k_deg_init(float* deg, int* cnt) {
  int i = blockIdx.x * 256 + threadIdx.x;
  if (i < NN) { deg[i] = 1.0f; cnt[i] = 0; }  // self-loop weight, zero histogram
}
__global__ __launch_bounds__(256) void k_deg_acc(const int* __restrict__ dst,
                                                 const float* __restrict__ w,
                                                 float* __restrict__ deg,
                                                 int* __restrict__ cnt) {
  int e = blockIdx.x * 256 + threadIdx.x;
  if (e < EE) {
    int d = dst[e];
    unsafeAtomicAdd(&deg[d], w[e]);
    atomicAdd(&cnt[d], 1);
  }
}

// ---------------- CSR build: scan (fused dinv) + fill ----------------
__global__ __launch_bounds__(256) void k_scan1(const int* __restrict__ cnt, int* __restrict__ loc,
                                               int* __restrict__ blkSum, float* __restrict__ deg) {
  __shared__ int s[256];
  int i = blockIdx.x * 256 + threadIdx.x;
  if (i < NN) { float d = deg[i]; deg[i] = d > 0.f ? rsqrtf(d) : 0.f; }  // fused dinv
  int v = (i < NN) ? cnt[i] : 0;
  s[threadIdx.x] = v;
  __syncthreads();
#pragma unroll
  for (int d = 1; d < 256; d <<= 1) {
    int t = (threadIdx.x >= d) ? s[threadIdx.x - d] : 0;
    __syncthreads();
    s[threadIdx.x] += t;
    __syncthreads();
  }
  if (i < NN) loc[i] = s[threadIdx.x] - v;  // exclusive
  if (threadIdx.x == 255) blkSum[blockIdx.x] = s[255];
}
__global__ __launch_bounds__(512) void k_scan2(int* __restrict__ blkSum, int* __restrict__ blkOff, int nb) {
  __shared__ int s[512];
  int v = (threadIdx.x < nb) ? blkSum[threadIdx.x] : 0;
  s[threadIdx.x] = v;
  __syncthreads();
#pragma unroll
  for (int d = 1; d < 512; d <<= 1) {
    int t = (threadIdx.x >= d) ? s[threadIdx.x - d] : 0;
    __syncthreads();
    s[threadIdx.x] += t;
    __syncthreads();
  }
  if (threadIdx.x < nb) blkOff[threadIdx.x] = s[threadIdx.x] - v;  // exclusive
}
__global__ __launch_bounds__(256) void k_scan3(const int* __restrict__ loc, const int* __restrict__ blkOff,
                                               int* __restrict__ rowptr, int* __restrict__ cursor) {
  int i = blockIdx.x * 256 + threadIdx.x;
  if (i < NN) {
    int v = loc[i] + blkOff[blockIdx.x];
    rowptr[i] = v;
    cursor[i] = v;
  }
}
__global__ __launch_bounds__(256) void k_fill(const int* __restrict__ src, const int* __restrict__ dst,
                                              const float* __restrict__ w, const float* __restrict__ dinv,
                                              int* __restrict__ cursor, int2* __restrict__ epack) {
  int e = blockIdx.x * 256 + threadIdx.x;
  if (e >= EE) return;
  int s = src[e], d = dst[e];
  int pos = atomicAdd(&cursor[d], 1);
  float coef = dinv[s] * w[e] * dinv[d];
  int2 m; m.x = s; m.y = __float_as_int(coef);
  epack[pos] = m;
}

// ---------------- packs ----------------
__global__ __launch_bounds__(256) void k_pack_w1t(const float* __restrict__ W1, unsigned short* __restrict__ W1T) {
  int i = blockIdx.x * 256 + threadIdx.x;  // 128*128
  if (i < FF * FF) {
    int col = i >> 7, k = i & 127;
    W1T[i] = f2bf(W1[k * FF + col]);
  }
}
// H0 f32 -> bf16 into A2 cols [128,384)
__global__ __launch_bounds__(256) void k_pack_h0(const float* __restrict__ H0, unsigned short* __restrict__ A2) {
  int q = blockIdx.x * 256 + threadIdx.x;  // quad over NN*64
  if (q >= NN * 64) return;
  int n = q >> 6, c4 = (q & 63) * 4;
  v4f v = *(const v4f*)(H0 + (size_t)n * 256 + c4);
  ushort4 o; o.x = f2bf(v.x); o.y = f2bf(v.y); o.z = f2bf(v.z); o.w = f2bf(v.w);
  *(ushort4*)(A2 + (size_t)n * KG + 128 + c4) = o;
}
// B^T, gate-interleaved: col = (s&15) + 16*g + 64*(s>>4);  BT[col][k] (k<128 -> W_g, else Th_g)
__global__ __launch_bounds__(256) void k_pack_bt(const float* __restrict__ Wi, const float* __restrict__ Wf,
                                                 const float* __restrict__ Wc, const float* __restrict__ Wo,
                                                 const float* __restrict__ Ti, const float* __restrict__ Tf,
                                                 const float* __restrict__ Tc, const float* __restrict__ To,
                                                 unsigned short* __restrict__ BT) {
  int i = blockIdx.x * 256 + threadIdx.x;  // 1024*384
  if (i >= NCOL * KG) return;
  int col = i / KG, k = i - col * KG;
  int th = col >> 6, rem = col & 63, g = rem >> 4, slo = rem & 15;
  int s = th * 16 + slo;
  const float* Wp = (g == 0) ? Wi : (g == 1) ? Wf : (g == 2) ? Wc : Wo;
  const float* Tp = (g == 0) ? Ti : (g == 1) ? Tf : (g == 2) ? Tc : To;
  float v = (k < FF) ? Wp[(size_t)k * SS + s] : Tp[(size_t)(k - FF) * SS + s];
  BT[i] = f2bf(v);
}
__global__ __launch_bounds__(256) void k_pack_bias(const float* bci, const float* bcf, const float* bcc, const float* bco,
                                                   const float* bi, const float* bf, const float* bc_, const float* bo,
                                                   float* biasP) {
  int col = blockIdx.x * 256 + threadIdx.x;
  if (col >= NCOL) return;
  int th = col >> 6, rem = col & 63, g = rem >> 4, slo = rem & 15;
  int s = th * 16 + slo;
  const float* P = (g == 0) ? bci : (g == 1) ? bcf : (g == 2) ? bcc : bco;
  const float* Q = (g == 0) ? bi : (g == 1) ? bf : (g == 2) ? bc_ : bo;
  biasP[col] = P[s] + Q[s];
}
__global__ __launch_bounds__(256) void k_pack_wlt(const float* __restrict__ Wl, unsigned short* __restrict__ WlT) {
  int i = blockIdx.x * 256 + threadIdx.x;  // 32*256
  if (i >= CC * SS) return;
  int c = i >> 8, k = i & 255;
  WlT[i] = f2bf(Wl[(size_t)k * CC + c]);
}

// ---------------- GEMM1: xw = f2bf(x) @ W1, fused fp32->bf16 pack (reg-staged, swizzled LDS) ----------------
__global__ __launch_bounds__(256) void k_gemm1(const float* __restrict__ x,
                                               const unsigned short* __restrict__ BT,
                                               unsigned short* __restrict__ Cout) {
  __shared__ unsigned short As[128 * 128];
  const int t = threadIdx.x;
  const int wave = t >> 6, lane = t & 63;
  const int wr = wave >> 1, wc = wave & 1;
  const int l15 = lane & 15, l4 = lane >> 4;
  const int row0 = blockIdx.x * 128;
  // reg-stage fp32 x -> bf16 LDS, XOR-swizzled. 8 rounds x (16 rows x 16 chunks).
  {
    const int rr = t >> 4, c8 = t & 15;
#pragma unroll
    for (int c = 0; c < 8; ++c) {
      int row = c * 16 + rr;
      int ar = row0 + row; if (ar >= NN) ar = NN - 1;
      const float* xp = x + (size_t)ar * 128 + c8 * 8;
      v4f f0 = *(const v4f*)(xp);
      v4f f1 = *(const v4f*)(xp + 4);
      u8s u;
      u[0] = f2bf(f0.x); u[1] = f2bf(f0.y); u[2] = f2bf(f0.z); u[3] = f2bf(f0.w);
      u[4] = f2bf(f1.x); u[5] = f2bf(f1.y); u[6] = f2bf(f1.z); u[7] = f2bf(f1.w);
      int sc = c8 ^ (row & 7);
      *(u8s*)&As[row * 128 + sc * 8] = u;
    }
  }
  __syncthreads();
  v4f acc[4][4];
  v4f zero = {0.f, 0.f, 0.f, 0.f};
#pragma unroll
  for (int m = 0; m < 4; ++m)
#pragma unroll
    for (int n = 0; n < 4; ++n) acc[m][n] = zero;
#pragma unroll
  for (int kt = 0; kt < 4; ++kt) {
    v8s a[4], b[4];
#pragma unroll
    for (int m = 0; m < 4; ++m) {
      int row = wr * 64 + m * 16 + l15;
      int j8 = kt * 4 + l4;
      a[m] = *(const v8s*)&As[row * 128 + ((j8 ^ (row & 7)) * 8)];
    }
#pragma unroll
    for (int n = 0; n < 4; ++n)
      b[n] = *(const v8s*)&BT[(size_t)(wc * 64 + n * 16 + l15) * 128 + kt * 32 + l4 * 8];
#pragma unroll
    for (int m = 0; m < 4; ++m)
#pragma unroll
      for (int n = 0; n < 4; ++n)
        acc[m][n] = __builtin_amdgcn_mfma_f32_16x16x32_bf16(a[m], b[n], acc[m][n], 0, 0, 0);
  }
#pragma unroll
  for (int m = 0; m < 4; ++m) {
#pragma unroll
    for (int r = 0; r < 4; ++r) {
      int row = row0 + wr * 64 + m * 16 + l4 * 4 + r;
      if (row < NN) {
#pragma unroll
        for (int n = 0; n < 4; ++n)
          Cout[(size_t)row * 128 + wc * 64 + n * 16 + l15] = f2bf(acc[m][n][r]);
      }
    }
  }
}

// ---------------- CSR gather (SpMM): one wave per dst node, 4-way ILP ----------------
__global__ __launch_bounds__(256) void k_gather(const unsigned short* __restrict__ xwb,
                                                const int2* __restrict__ epack,
                                                const int* __restrict__ rowptr, const int* __restrict__ cnt,
                                                const float* __restrict__ dinv, const float* __restrict__ b1,
                                                unsigned short* __restrict__ A2) {
  const int wave = threadIdx.x >> 6, lane = threadIdx.x & 63;
  const int n = blockIdx.x * 4 + wave;  // NN divisible by 4
  const int c0 = lane * 2;
  const int base = rowptr[n];
  const int len = cnt[n];
  float di = dinv[n];
  float slf = di * di;
  ushort2 xv = *(const ushort2*)(xwb + (size_t)n * 128 + c0);
  float a0 = b1[c0] + slf * bf2f(xv.x);
  float a1 = b1[c0 + 1] + slf * bf2f(xv.y);
  float p0 = 0.f, p1 = 0.f, q0 = 0.f, q1 = 0.f, r0 = 0.f, r1 = 0.f;
  int j = 0;
  for (; j + 4 <= len; j += 4) {
    int2 m0 = epack[base + j];
    int2 m1 = epack[base + j + 1];
    int2 m2 = epack[base + j + 2];
    int2 m3 = epack[base + j + 3];
    ushort2 v0 = *(const ushort2*)(xwb + (size_t)m0.x * 128 + c0);
    ushort2 v1 = *(const ushort2*)(xwb + (size_t)m1.x * 128 + c0);
    ushort2 v2 = *(const ushort2*)(xwb + (size_t)m2.x * 128 + c0);
    ushort2 v3 = *(const ushort2*)(xwb + (size_t)m3.x * 128 + c0);
    float cf0 = __int_as_float(m0.y), cf1 = __int_as_float(m1.y);
    float cf2 = __int_as_float(m2.y), cf3 = __int_as_float(m3.y);
    a0 += cf0 * bf2f(v0.x); a1 += cf0 * bf2f(v0.y);
    p0 += cf1 * bf2f(v1.x); p1 += cf1 * bf2f(v1.y);
    q0 += cf2 * bf2f(v2.x); q1 += cf2 * bf2f(v2.y);
    r0 += cf3 * bf2f(v3.x); r1 += cf3 * bf2f(v3.y);
  }
  for (; j < len; ++j) {
    int2 m0 = epack[base + j];
    ushort2 v0 = *(const ushort2*)(xwb + (size_t)m0.x * 128 + c0);
    float cf0 = __int_as_float(m0.y);
    a0 += cf0 * bf2f(v0.x);
    a1 += cf0 * bf2f(v0.y);
  }
  a0 += (p0 + q0) + r0;
  a1 += (p1 + q1) + r1;
  ushort2 o; o.x = f2bf(a0); o.y = f2bf(a1);
  *(ushort2*)(A2 + (size_t)n * KG + c0) = o;
}

// ---------------- gates GEMM + fused LSTM epilogue ----------------
// NO LDS, NO BARRIERS: A and B fragments loaded directly from global (L1/L2-resident),
// per-lane 64-bit bases hoisted, all K offsets fold into imm offsets. XCD-chunked mapping.
__global__ __launch_bounds__(256, 3) void k_gates(const unsigned short* __restrict__ A2,
                                                  const unsigned short* __restrict__ BT,
                                                  const float* __restrict__ biasP, const float* __restrict__ C0,
                                                  float* __restrict__ Hn, float* __restrict__ Cn,
                                                  unsigned short* __restrict__ hrelu) {
  const int g = blockIdx.x;
  const int xcd = g & 7, li = g >> 3;       // li 0..783
  const int xl = li >> 3, y = li & 7;       // per-XCD: y fastest -> A-panel reused from L2
  const int xb = xcd * 98 + xl;
  if (xb >= 782) return;
  const int t = threadIdx.x;
  const int wave = t >> 6, lane = t & 63;
  const int wr = wave >> 1, wc = wave & 1;
  const int l15 = lane & 15, l4 = lane >> 4;
  const int row0 = xb * 128, crow0 = y * 128;

  const unsigned short* Ab[4];
#pragma unroll
  for (int m = 0; m < 4; ++m) {
    int ar = row0 + wr * 64 + m * 16 + l15;
    if (ar >= NN) ar = NN - 1;              // clamp: garbage rows never stored
    Ab[m] = A2 + (size_t)ar * KG + l4 * 8;
  }
  const unsigned short* Bb[4];
#pragma unroll
  for (int n = 0; n < 4; ++n)
    Bb[n] = BT + (size_t)(crow0 + wc * 64 + n * 16 + l15) * KG + l4 * 8;

  v4f acc[4][4];
  v4f zero = {0.f, 0.f, 0.f, 0.f};
#pragma unroll
  for (int m = 0; m < 4; ++m)
#pragma unroll
    for (int n = 0; n < 4; ++n) acc[m][n] = zero;

#pragma unroll
  for (int kt = 0; kt < 12; ++kt) {         // K-step 32, imm offset kt*64B (max 704, fits 13-bit)
    v8s a[4], b[4];
#pragma unroll
    for (int m = 0; m < 4; ++m) a[m] = *(const v8s*)(Ab[m] + kt * 32);
#pragma unroll
    for (int n = 0; n < 4; ++n) b[n] = *(const v8s*)(Bb[n] + kt * 32);
#pragma unroll
    for (int m = 0; m < 4; ++m)
#pragma unroll
      for (int n = 0; n < 4; ++n)
        acc[m][n] = __builtin_amdgcn_mfma_f32_16x16x32_bf16(a[m], b[n], acc[m][n], 0, 0, 0);
  }

  // epilogue: n-frag index == gate (0:i 1:f 2:c 3:o), s = (2*y+wc)*16 + l15
  const int s = (2 * y + wc) * 16 + l15;
  const int cb = crow0 + wc * 64 + l15;
  float bi = biasP[cb], bfv = biasP[cb + 16], bcv = biasP[cb + 32], bov = biasP[cb + 48];
#pragma unroll
  for (int m = 0; m < 4; ++m) {
#pragma unroll
    for (int r = 0; r < 4; ++r) {
      int row = row0 + wr * 64 + m * 16 + l4 * 4 + r;
      if (row < NN) {
        float I  = sigmoidf_(acc[m][0][r] + bi);
        float Fg = sigmoidf_(acc[m][1][r] + bfv);
        float T  = tanhf_(acc[m][2][r] + bcv);
        float O  = sigmoidf_(acc[m][3][r] + bov);
        size_t idx = (size_t)row * SS + s;
        float c0 = C0[idx];
        float cn = Fg * c0 + I * T;
        float hn = O * tanhf_(cn);
        Cn[idx] = cn;
        Hn[idx] = hn;
        hrelu[idx] = f2bf(hn > 0.f ? hn : 0.f);
      }
    }
  }
}

// ---------------- output linear + fused softmax ----------------
// whole 128x256 A-tile staged once (swizzled), single barrier
__global__ __launch_bounds__(256) void k_linsoft(const unsigned short* __restrict__ Arelu,
                                                 const unsigned short* __restrict__ WlT,
                                                 const float* __restrict__ bl, float* __restrict__ out) {
  __shared__ unsigned short As[128 * 256];
  const int t = threadIdx.x;
  const int wave = t >> 6, lane = t & 63;
  const int l15 = lane & 15, l4 = lane >> 4;
  const int row0 = blockIdx.x * 128;
#pragma unroll
  for (int c = 0; c < 16; ++c) {
    int slot = c * 256 + t;
    int row = slot >> 5, chunk = slot & 31;
    int ar = row0 + row; if (ar >= NN) ar = NN - 1;
    int sc = chunk ^ (row & 7);
    gload_lds16(Arelu + (size_t)ar * 256 + sc * 8, &As[row * 256 + chunk * 8]);
  }
  v8s bfr[8][2];
#pragma unroll
  for (int ks = 0; ks < 8; ++ks)
#pragma unroll
    for (int n = 0; n < 2; ++n)
      bfr[ks][n] = *(const v8s*)&WlT[(size_t)(n * 16 + l15) * 256 + ks * 32 + l4 * 8];
  v4f acc[2][2];
  v4f zero = {0.f, 0.f, 0.f, 0.f};
#pragma unroll
  for (int m = 0; m < 2; ++m)
#pragma unroll
    for (int n = 0; n < 2; ++n) acc[m][n] = zero;
  __syncthreads();
#pragma unroll
  for (int ks = 0; ks < 8; ++ks) {
    v8s a[2];
#pragma unroll
    for (int m = 0; m < 2; ++m) {
      int row = wave * 32 + m * 16 + l15;
      int j8 = ks * 4 + l4;
      a[m] = *(const v8s*)&As[row * 256 + ((j8 ^ (row & 7)) * 8)];
    }
#pragma unroll
    for (int m = 0; m < 2; ++m)
#pragma unroll
      for (int n = 0; n < 2; ++n)
        acc[m][n] = __builtin_amdgcn_mfma_f32_16x16x32_bf16(a[m], bfr[ks][n], acc[m][n], 0, 0, 0);
  }
  float b0 = bl[l15], b1v = bl[16 + l15];
#pragma unroll
  for (int m = 0; m < 2; ++m) {
#pragma unroll
    for (int r = 0; r < 4; ++r) {
      int row = row0 + wave * 32 + m * 16 + l4 * 4 + r;
      float v0 = acc[m][0][r] + b0;
      float v1 = acc[m][1][r] + b1v;
      float mx = fmaxf(v0, v1);
#pragma unroll
      for (int d = 1; d < 16; d <<= 1) mx = fmaxf(mx, __shfl_xor(mx, d, 64));
      float e0 = __expf(v0 - mx), e1 = __expf(v1 - mx);
      float sm = e0 + e1;
#pragma unroll
      for (int d = 1; d < 16; d <<= 1) sm += __shfl_xor(sm, d, 64);
      if (row < NN) {
        out[(size_t)row * 32 + l15] = e0 / sm;
        out[(size_t)row * 32 + 16 + l15] = e1 / sm;
      }
    }
  }
}

extern "C" void kernel_launch(void* const* d_in, const int* in_sizes, int n_in,
                              void* d_out, int out_size, void* d_ws, size_t ws_size,
                              hipStream_t stream) {
  (void)in_sizes; (void)n_in; (void)out_size; (void)ws_size;
  const float* x   = (const float*)d_in[0];
  const int*   ei  = (const int*)d_in[1];
  const float* ew  = (const float*)d_in[2];
  const float* H0  = (const float*)d_in[3];
  const float* C0  = (const float*)d_in[4];
  const float* W1  = (const float*)d_in[5];
  const float* b1  = (const float*)d_in[6];
  const float* Wi  = (const float*)d_in[7];
  const float* Ti  = (const float*)d_in[8];
  const float* bci = (const float*)d_in[9];
  const float* bii = (const float*)d_in[10];
  const float* Wf  = (const float*)d_in[11];
  const float* Tf  = (const float*)d_in[12];
  const float* bcf = (const float*)d_in[13];
  const float* bif = (const float*)d_in[14];
  const float* Wc  = (const float*)d_in[15];
  const float* Tc  = (const float*)d_in[16];
  const float* bcc = (const float*)d_in[17];
  const float* bic = (const float*)d_in[18];
  const float* Wo  = (const float*)d_in[19];
  const float* To  = (const float*)d_in[20];
  const float* bco = (const float*)d_in[21];
  const float* bio = (const float*)d_in[22];
  const float* Wl  = (const float*)d_in[23];
  const float* bl  = (const float*)d_in[24];

  const int* srcI = ei;
  const int* dstI = ei + EE;

  char* ws = (char*)d_ws;
  size_t off = 0;
  auto carve = [&](size_t bytes) -> char* {
    char* p = ws + off;
    off += (bytes + 255) & ~(size_t)255;
    return p;
  };
  float* dinv          = (float*)carve((size_t)NN * 4);
  int*   cnt           = (int*)carve((size_t)NN * 4);
  int*   loc           = (int*)carve((size_t)NN * 4);
  int*   blkSum        = (int*)carve(512 * 4);
  int*   blkOff        = (int*)carve(512 * 4);
  int*   rowptr        = (int*)carve((size_t)NN * 4);
  int*   cursor        = (int*)carve((size_t)NN * 4);
  int2*  epack         = (int2*)carve((size_t)EE * 8);
  unsigned short* W1T  = (unsigned short*)carve((size_t)FF * FF * 2);
  unsigned short* xwb  = (unsigned short*)carve((size_t)NN * FF * 2);
  unsigned short* A2   = (unsigned short*)carve((size_t)NN * KG * 2);
  unsigned short* BT   = (unsigned short*)carve((size_t)NCOL * KG * 2);
  float* biasP         = (float*)carve((size_t)NCOL * 4);
  unsigned short* WlT  = (unsigned short*)carve((size_t)CC * SS * 2);
  unsigned short* hrelu = (unsigned short*)carve((size_t)NN * SS * 2);

  float* outSm = (float*)d_out;
  float* HnO = outSm + (size_t)NN * CC;
  float* CnO = HnO + (size_t)NN * SS;

  const int NB = (NN + 255) / 256;  // 391

  k_deg_init<<<NB, 256, 0, stream>>>(dinv, cnt);
  k_deg_acc<<<6250, 256, 0, stream>>>(dstI, ew, dinv, cnt);
  // CSR build (k_scan1 also finalizes dinv)
  k_scan1<<<NB, 256, 0, stream>>>(cnt, loc, blkSum, dinv);
  k_scan2<<<1, 512, 0, stream>>>(blkSum, blkOff, NB);
  k_scan3<<<NB, 256, 0, stream>>>(loc, blkOff, rowptr, cursor);
  k_fill<<<6250, 256, 0, stream>>>(srcI, dstI, ew, dinv, cursor, epack);
  // dense path
  k_pack_w1t<<<64, 256, 0, stream>>>(W1, W1T);
  k_gemm1<<<782, 256, 0, stream>>>(x, W1T, xwb);
  k_gather<<<25000, 256, 0, stream>>>(xwb, epack, rowptr, cnt, dinv, b1, A2);
  k_pack_h0<<<25000, 256, 0, stream>>>(H0, A2);
  k_pack_bt<<<1536, 256, 0, stream>>>(Wi, Wf, Wc, Wo, Ti, Tf, Tc, To, BT);
  k_pack_bias<<<4, 256, 0, stream>>>(bci, bcf, bcc, bco, bii, bif, bic, bio, biasP);
  k_pack_wlt<<<32, 256, 0, stream>>>(Wl, WlT);
  k_gates<<<6272, 256, 0, stream>>>(A2, BT, biasP, C0, HnO, CnO, hrelu);
  k_linsoft<<<782, 256, 0, stream>>>(hrelu, WlT, bl, outSm);
}

// Round 5
// 617.006 us; speedup vs baseline: 1.2143x; 1.2143x over previous
//
#include <hip/hip_runtime.h>

#define NN 100000
#define EE 1600000
#define FF 128
#define SS 256
#define CC 32
#define KG 384     // gates GEMM K = F + S
#define NCOL 1024  // gates GEMM N = 4 gates * S

typedef __attribute__((ext_vector_type(8))) short v8s;
typedef __attribute__((ext_vector_type(8))) unsigned short u8s;
typedef __attribute__((ext_vector_type(4))) float v4f;

__device__ __forceinline__ void gload_lds16(const void* g, void* l) {
  __builtin_amdgcn_global_load_lds(
      (const __attribute__((address_space(1))) void*)g,
      (__attribute__((address_space(3))) void*)l, 16, 0, 0);
}

__device__ __forceinline__ unsigned short f2bf(float f) {
  unsigned int u = __float_as_uint(f);
  u += 0x7FFF + ((u >> 16) & 1);  // RNE
  return (unsigned short)(u >> 16);
}
__device__ __forceinline__ float bf2f(unsigned short u) {
  return __uint_as_float(((unsigned int)u) << 16);
}
__device__ __forceinline__ float sigmoidf_(float x) { return 1.0f / (1.0f + __expf(-x)); }
__device__ __forceinline__ float tanhf_(float x) {
  float ax = fabsf(x);
  float e = __expf(2.0f * ax);
  float t = 1.0f - 2.0f / (e + 1.0f);
  return copysignf(t, x);
}

// ---------------- degree / norm + edge histogram ----------------
__global__ __launch_bounds__(256) void k_deg_init(float* deg, int* cnt) {
  int i = blockIdx.x * 256 + threadIdx.x;
  if (i < NN) { deg[i] = 1.0f; cnt[i] = 0; }
}
__global__ __launch_bounds__(256) void k_deg_acc(const int* __restrict__ dst,
                                                 const float* __restrict__ w,
                                                 float* __restrict__ deg,
                                                 int* __restrict__ cnt) {
  int e = blockIdx.x * 256 + threadIdx.x;
  if (e < EE) {
    int d = dst[e];
    unsafeAtomicAdd(&deg[d], w[e]);
    atomicAdd(&cnt[d], 1);
  }
}

// ---------------- CSR build: scan (fused dinv) + fill ----------------
__global__ __launch_bounds__(256) void k_scan1(const int* __restrict__ cnt, int* __restrict__ loc,
                                               int* __restrict__ blkSum, float* __restrict__ deg) {
  __shared__ int s[256];
  int i = blockIdx.x * 256 + threadIdx.x;
  if (i < NN) { float d = deg[i]; deg[i] = d > 0.f ? rsqrtf(d) : 0.f; }  // fused dinv
  int v = (i < NN) ? cnt[i] : 0;
  s[threadIdx.x] = v;
  __syncthreads();
#pragma unroll
  for (int d = 1; d < 256; d <<= 1) {
    int t = (threadIdx.x >= d) ? s[threadIdx.x - d] : 0;
    __syncthreads();
    s[threadIdx.x] += t;
    __syncthreads();
  }
  if (i < NN) loc[i] = s[threadIdx.x] - v;  // exclusive
  if (threadIdx.x == 255) blkSum[blockIdx.x] = s[255];
}
__global__ __launch_bounds__(512) void k_scan2(int* __restrict__ blkSum, int* __restrict__ blkOff, int nb) {
  __shared__ int s[512];
  int v = (threadIdx.x < nb) ? blkSum[threadIdx.x] : 0;
  s[threadIdx.x] = v;
  __syncthreads();
#pragma unroll
  for (int d = 1; d < 512; d <<= 1) {
    int t = (threadIdx.x >= d) ? s[threadIdx.x - d] : 0;
    __syncthreads();
    s[threadIdx.x] += t;
    __syncthreads();
  }
  if (threadIdx.x < nb) blkOff[threadIdx.x] = s[threadIdx.x] - v;  // exclusive
}
__global__ __launch_bounds__(256) void k_scan3(const int* __restrict__ loc, const int* __restrict__ blkOff,
                                               int* __restrict__ rowptr, int* __restrict__ cursor) {
  int i = blockIdx.x * 256 + threadIdx.x;
  if (i < NN) {
    int v = loc[i] + blkOff[blockIdx.x];
    rowptr[i] = v;
    cursor[i] = v;
  }
}
__global__ __launch_bounds__(256) void k_fill(const int* __restrict__ src, const int* __restrict__ dst,
                                              const float* __restrict__ w, const float* __restrict__ dinv,
                                              int* __restrict__ cursor, int2* __restrict__ epack) {
  int e = blockIdx.x * 256 + threadIdx.x;
  if (e >= EE) return;
  int s = src[e], d = dst[e];
  int pos = atomicAdd(&cursor[d], 1);
  float coef = dinv[s] * w[e] * dinv[d];
  int2 m; m.x = s; m.y = __float_as_int(coef);
  epack[pos] = m;
}

// ---------------- packs ----------------
__global__ __launch_bounds__(256) void k_pack_w1t(const float* __restrict__ W1, unsigned short* __restrict__ W1T) {
  int i = blockIdx.x * 256 + threadIdx.x;  // 128*128
  if (i < FF * FF) {
    int col = i >> 7, k = i & 127;
    W1T[i] = f2bf(W1[k * FF + col]);
  }
}
// B^T plane-major: BTk[p][col][8], p=k/8, col = (s&15) + 16*g + 64*(s>>4)
// -> a wave b-frag load touches 8 cache lines (16 lanes x 16B contiguous per plane)
__global__ __launch_bounds__(256) void k_pack_btk(const float* __restrict__ Wi, const float* __restrict__ Wf,
                                                  const float* __restrict__ Wc, const float* __restrict__ Wo,
                                                  const float* __restrict__ Ti, const float* __restrict__ Tf,
                                                  const float* __restrict__ Tc, const float* __restrict__ To,
                                                  unsigned short* __restrict__ BTk) {
  int i = blockIdx.x * 256 + threadIdx.x;  // 1024*384
  if (i >= NCOL * KG) return;
  int col = i / KG, k = i - col * KG;
  int th = col >> 6, rem = col & 63, g = rem >> 4, slo = rem & 15;
  int s = th * 16 + slo;
  const float* Wp = (g == 0) ? Wi : (g == 1) ? Wf : (g == 2) ? Wc : Wo;
  const float* Tp = (g == 0) ? Ti : (g == 1) ? Tf : (g == 2) ? Tc : To;
  float v = (k < FF) ? Wp[(size_t)k * SS + s] : Tp[(size_t)(k - FF) * SS + s];
  int p = k >> 3, j = k & 7;
  BTk[((size_t)p * NCOL + col) * 8 + j] = f2bf(v);
}
__global__ __launch_bounds__(256) void k_pack_bias(const float* bci, const float* bcf, const float* bcc, const float* bco,
                                                   const float* bi, const float* bf, const float* bc_, const float* bo,
                                                   float* biasP) {
  int col = blockIdx.x * 256 + threadIdx.x;
  if (col >= NCOL) return;
  int th = col >> 6, rem = col & 63, g = rem >> 4, slo = rem & 15;
  int s = th * 16 + slo;
  const float* P = (g == 0) ? bci : (g == 1) ? bcf : (g == 2) ? bcc : bco;
  const float* Q = (g == 0) ? bi : (g == 1) ? bf : (g == 2) ? bc_ : bo;
  biasP[col] = P[s] + Q[s];
}
__global__ __launch_bounds__(256) void k_pack_wlt(const float* __restrict__ Wl, unsigned short* __restrict__ WlT) {
  int i = blockIdx.x * 256 + threadIdx.x;  // 32*256
  if (i >= CC * SS) return;
  int c = i >> 8, k = i & 255;
  WlT[i] = f2bf(Wl[(size_t)k * CC + c]);
}

// ---------------- GEMM1: xw = f2bf(x) @ W1, fused fp32->bf16 pack ----------------
__global__ __launch_bounds__(256) void k_gemm1(const float* __restrict__ x,
                                               const unsigned short* __restrict__ BT,
                                               unsigned short* __restrict__ Cout) {
  __shared__ unsigned short As[128 * 128];
  const int t = threadIdx.x;
  const int wave = t >> 6, lane = t & 63;
  const int wr = wave >> 1, wc = wave & 1;
  const int l15 = lane & 15, l4 = lane >> 4;
  const int row0 = blockIdx.x * 128;
  {
    const int rr = t >> 4, c8 = t & 15;
#pragma unroll
    for (int c = 0; c < 8; ++c) {
      int row = c * 16 + rr;
      int ar = row0 + row; if (ar >= NN) ar = NN - 1;
      const float* xp = x + (size_t)ar * 128 + c8 * 8;
      v4f f0 = *(const v4f*)(xp);
      v4f f1 = *(const v4f*)(xp + 4);
      u8s u;
      u[0] = f2bf(f0.x); u[1] = f2bf(f0.y); u[2] = f2bf(f0.z); u[3] = f2bf(f0.w);
      u[4] = f2bf(f1.x); u[5] = f2bf(f1.y); u[6] = f2bf(f1.z); u[7] = f2bf(f1.w);
      int sc = c8 ^ (row & 7);
      *(u8s*)&As[row * 128 + sc * 8] = u;
    }
  }
  __syncthreads();
  v4f acc[4][4];
  v4f zero = {0.f, 0.f, 0.f, 0.f};
#pragma unroll
  for (int m = 0; m < 4; ++m)
#pragma unroll
    for (int n = 0; n < 4; ++n) acc[m][n] = zero;
#pragma unroll
  for (int kt = 0; kt < 4; ++kt) {
    v8s a[4], b[4];
#pragma unroll
    for (int m = 0; m < 4; ++m) {
      int row = wr * 64 + m * 16 + l15;
      int j8 = kt * 4 + l4;
      a[m] = *(const v8s*)&As[row * 128 + ((j8 ^ (row & 7)) * 8)];
    }
#pragma unroll
    for (int n = 0; n < 4; ++n)
      b[n] = *(const v8s*)&BT[(size_t)(wc * 64 + n * 16 + l15) * 128 + kt * 32 + l4 * 8];
#pragma unroll
    for (int m = 0; m < 4; ++m)
#pragma unroll
      for (int n = 0; n < 4; ++n)
        acc[m][n] = __builtin_amdgcn_mfma_f32_16x16x32_bf16(a[m], b[n], acc[m][n], 0, 0, 0);
  }
#pragma unroll
  for (int m = 0; m < 4; ++m) {
#pragma unroll
    for (int r = 0; r < 4; ++r) {
      int row = row0 + wr * 64 + m * 16 + l4 * 4 + r;
      if (row < NN) {
#pragma unroll
        for (int n = 0; n < 4; ++n)
          Cout[(size_t)row * 128 + wc * 64 + n * 16 + l15] = f2bf(acc[m][n][r]);
      }
    }
  }
}

// ---------------- CSR gather (SpMM) + fused H0 pack: one wave per dst node ----------------
__global__ __launch_bounds__(256) void k_gather(const unsigned short* __restrict__ xwb,
                                                const int2* __restrict__ epack,
                                                const int* __restrict__ rowptr, const int* __restrict__ cnt,
                                                const float* __restrict__ dinv, const float* __restrict__ b1,
                                                const float* __restrict__ H0,
                                                unsigned short* __restrict__ A2) {
  const int wave = threadIdx.x >> 6, lane = threadIdx.x & 63;
  const int n = blockIdx.x * 4 + wave;  // NN divisible by 4
  const int c0 = lane * 2;
  const int base = rowptr[n];
  const int len = cnt[n];
  float di = dinv[n];
  float slf = di * di;
  ushort2 xv = *(const ushort2*)(xwb + (size_t)n * 128 + c0);
  float a0 = b1[c0] + slf * bf2f(xv.x);
  float a1 = b1[c0 + 1] + slf * bf2f(xv.y);
  float p0 = 0.f, p1 = 0.f, q0 = 0.f, q1 = 0.f, r0 = 0.f, r1 = 0.f;
  int j = 0;
  for (; j + 4 <= len; j += 4) {
    int2 m0 = epack[base + j];
    int2 m1 = epack[base + j + 1];
    int2 m2 = epack[base + j + 2];
    int2 m3 = epack[base + j + 3];
    ushort2 v0 = *(const ushort2*)(xwb + (size_t)m0.x * 128 + c0);
    ushort2 v1 = *(const ushort2*)(xwb + (size_t)m1.x * 128 + c0);
    ushort2 v2 = *(const ushort2*)(xwb + (size_t)m2.x * 128 + c0);
    ushort2 v3 = *(const ushort2*)(xwb + (size_t)m3.x * 128 + c0);
    float cf0 = __int_as_float(m0.y), cf1 = __int_as_float(m1.y);
    float cf2 = __int_as_float(m2.y), cf3 = __int_as_float(m3.y);
    a0 += cf0 * bf2f(v0.x); a1 += cf0 * bf2f(v0.y);
    p0 += cf1 * bf2f(v1.x); p1 += cf1 * bf2f(v1.y);
    q0 += cf2 * bf2f(v2.x); q1 += cf2 * bf2f(v2.y);
    r0 += cf3 * bf2f(v3.x); r1 += cf3 * bf2f(v3.y);
  }
  for (; j < len; ++j) {
    int2 m0 = epack[base + j];
    ushort2 v0 = *(const ushort2*)(xwb + (size_t)m0.x * 128 + c0);
    float cf0 = __int_as_float(m0.y);
    a0 += cf0 * bf2f(v0.x);
    a1 += cf0 * bf2f(v0.y);
  }
  a0 += (p0 + q0) + r0;
  a1 += (p1 + q1) + r1;
  ushort2 o; o.x = f2bf(a0); o.y = f2bf(a1);
  *(ushort2*)(A2 + (size_t)n * KG + c0) = o;
  // fused: H0 f32 -> bf16 into A2 cols [128,384)
  v4f hv = *(const v4f*)(H0 + (size_t)n * 256 + lane * 4);
  ushort4 ho; ho.x = f2bf(hv.x); ho.y = f2bf(hv.y); ho.z = f2bf(hv.z); ho.w = f2bf(hv.w);
  *(ushort4*)(A2 + (size_t)n * KG + 128 + lane * 4) = ho;
}

// ---------------- gates GEMM + fused LSTM epilogue ----------------
// A: 3-buffer LDS, 2-deep prefetch, counted vmcnt (never 0 in loop), raw s_barrier.
// B: direct from L2 in plane-major layout (8 lines/instr). XCD-chunked mapping.
__global__ __launch_bounds__(256, 3) void k_gates(const unsigned short* __restrict__ A2,
                                                  const unsigned short* __restrict__ BTk,
                                                  const float* __restrict__ biasP, const float* __restrict__ C0,
                                                  float* __restrict__ Hn, float* __restrict__ Cn,
                                                  unsigned short* __restrict__ hrelu) {
  __shared__ unsigned short As[3][128 * 64];
  const int g = blockIdx.x;
  const int xcd = g & 7, li = g >> 3;
  const int xl = li >> 3, y = li & 7;   // per-XCD: y fastest -> A-panel L2 reuse
  const int xb = xcd * 98 + xl;
  if (xb >= 782) return;
  const int t = threadIdx.x;
  const int wave = t >> 6, lane = t & 63;
  const int wr = wave >> 1, wc = wave & 1;
  const int l15 = lane & 15, l4 = lane >> 4;
  const int row0 = xb * 128, crow0 = y * 128;
  const int r_in = t >> 3, chunk = t & 7;

#define STAGE(buf, kt)                                                          \
  {                                                                             \
    _Pragma("unroll") for (int c = 0; c < 4; ++c) {                             \
      int row = c * 32 + r_in;                                                  \
      int ar = row0 + row; if (ar >= NN) ar = NN - 1;                           \
      int sc = chunk ^ (row & 7);                                               \
      gload_lds16(A2 + (size_t)ar * KG + (kt) * 64 + sc * 8,                    \
                  &As[buf][row * 64 + chunk * 8]);                              \
    }                                                                           \
  }

  const unsigned short* Bb[4];
#pragma unroll
  for (int n = 0; n < 4; ++n)
    Bb[n] = BTk + ((size_t)l4 * NCOL + (crow0 + wc * 64 + n * 16 + l15)) * 8;

  v4f acc[4][4];
  v4f zero = {0.f, 0.f, 0.f, 0.f};
#pragma unroll
  for (int m = 0; m < 4; ++m)
#pragma unroll
    for (int n = 0; n < 4; ++n) acc[m][n] = zero;

  STAGE(0, 0);
  STAGE(1, 1);
  asm volatile("s_waitcnt vmcnt(4)" ::: "memory");   // tile0 staged; tile1 in flight
  __builtin_amdgcn_sched_barrier(0);
  __builtin_amdgcn_s_barrier();
  asm volatile("" ::: "memory");

#pragma unroll
  for (int kt = 0; kt < 6; ++kt) {
    if (kt < 4) STAGE((kt + 2) % 3, kt + 2);         // 2-deep prefetch
    const int cur = kt % 3;
#pragma unroll
    for (int kk = 0; kk < 2; ++kk) {
      v8s a[4], b[4];
#pragma unroll
      for (int m = 0; m < 4; ++m) {
        int row = wr * 64 + m * 16 + l15;
        int j8 = kk * 4 + l4;
        a[m] = *(const v8s*)&As[cur][row * 64 + ((j8 ^ (row & 7)) * 8)];
      }
      const size_t poff = (size_t)((kt * 8 + kk * 4) * NCOL) * 8;
#pragma unroll
      for (int n = 0; n < 4; ++n) b[n] = *(const v8s*)(Bb[n] + poff);
#pragma unroll
      for (int m = 0; m < 4; ++m)
#pragma unroll
        for (int n = 0; n < 4; ++n)
          acc[m][n] = __builtin_amdgcn_mfma_f32_16x16x32_bf16(a[m], b[n], acc[m][n], 0, 0, 0);
    }
    if (kt < 5) {
      if (kt < 4) { asm volatile("s_waitcnt vmcnt(4)" ::: "memory"); }  // next tile staged, newest still flying
      else        { asm volatile("s_waitcnt vmcnt(0)" ::: "memory"); }  // tail
      __builtin_amdgcn_sched_barrier(0);
      __builtin_amdgcn_s_barrier();
      asm volatile("" ::: "memory");
    }
  }
#undef STAGE

  // epilogue: n-frag index == gate (0:i 1:f 2:c 3:o), s = (2*y+wc)*16 + l15
  const int s = (2 * y + wc) * 16 + l15;
  const int cb = crow0 + wc * 64 + l15;
  float bi = biasP[cb], bfv = biasP[cb + 16], bcv = biasP[cb + 32], bov = biasP[cb + 48];
#pragma unroll
  for (int m = 0; m < 4; ++m) {
#pragma unroll
    for (int r = 0; r < 4; ++r) {
      int row = row0 + wr * 64 + m * 16 + l4 * 4 + r;
      if (row < NN) {
        float I  = sigmoidf_(acc[m][0][r] + bi);
        float Fg = sigmoidf_(acc[m][1][r] + bfv);
        float T  = tanhf_(acc[m][2][r] + bcv);
        float O  = sigmoidf_(acc[m][3][r] + bov);
        size_t idx = (size_t)row * SS + s;
        float c0 = C0[idx];
        float cn = Fg * c0 + I * T;
        float hn = O * tanhf_(cn);
        Cn[idx] = cn;
        Hn[idx] = hn;
        hrelu[idx] = f2bf(hn > 0.f ? hn : 0.f);
      }
    }
  }
}

// ---------------- output linear + fused softmax ----------------
__global__ __launch_bounds__(256) void k_linsoft(const unsigned short* __restrict__ Arelu,
                                                 const unsigned short* __restrict__ WlT,
                                                 const float* __restrict__ bl, float* __restrict__ out) {
  __shared__ unsigned short As[128 * 256];
  const int t = threadIdx.x;
  const int wave = t >> 6, lane = t & 63;
  const int l15 = lane & 15, l4 = lane >> 4;
  const int row0 = blockIdx.x * 128;
#pragma unroll
  for (int c = 0; c < 16; ++c) {
    int slot = c * 256 + t;
    int row = slot >> 5, chunk = slot & 31;
    int ar = row0 + row; if (ar >= NN) ar = NN - 1;
    int sc = chunk ^ (row & 7);
    gload_lds16(Arelu + (size_t)ar * 256 + sc * 8, &As[row * 256 + chunk * 8]);
  }
  v8s bfr[8][2];
#pragma unroll
  for (int ks = 0; ks < 8; ++ks)
#pragma unroll
    for (int n = 0; n < 2; ++n)
      bfr[ks][n] = *(const v8s*)&WlT[(size_t)(n * 16 + l15) * 256 + ks * 32 + l4 * 8];
  v4f acc[2][2];
  v4f zero = {0.f, 0.f, 0.f, 0.f};
#pragma unroll
  for (int m = 0; m < 2; ++m)
#pragma unroll
    for (int n = 0; n < 2; ++n) acc[m][n] = zero;
  __syncthreads();
#pragma unroll
  for (int ks = 0; ks < 8; ++ks) {
    v8s a[2];
#pragma unroll
    for (int m = 0; m < 2; ++m) {
      int row = wave * 32 + m * 16 + l15;
      int j8 = ks * 4 + l4;
      a[m] = *(const v8s*)&As[row * 256 + ((j8 ^ (row & 7)) * 8)];
    }
#pragma unroll
    for (int m = 0; m < 2; ++m)
#pragma unroll
      for (int n = 0; n < 2; ++n)
        acc[m][n] = __builtin_amdgcn_mfma_f32_16x16x32_bf16(a[m], bfr[ks][n], acc[m][n], 0, 0, 0);
  }
  float b0 = bl[l15], b1v = bl[16 + l15];
#pragma unroll
  for (int m = 0; m < 2; ++m) {
#pragma unroll
    for (int r = 0; r < 4; ++r) {
      int row = row0 + wave * 32 + m * 16 + l4 * 4 + r;
      float v0 = acc[m][0][r] + b0;
      float v1 = acc[m][1][r] + b1v;
      float mx = fmaxf(v0, v1);
#pragma unroll
      for (int d = 1; d < 16; d <<= 1) mx = fmaxf(mx, __shfl_xor(mx, d, 64));
      float e0 = __expf(v0 - mx), e1 = __expf(v1 - mx);
      float sm = e0 + e1;
#pragma unroll
      for (int d = 1; d < 16; d <<= 1) sm += __shfl_xor(sm, d, 64);
      if (row < NN) {
        out[(size_t)row * 32 + l15] = e0 / sm;
        out[(size_t)row * 32 + 16 + l15] = e1 / sm;
      }
    }
  }
}

extern "C" void kernel_launch(void* const* d_in, const int* in_sizes, int n_in,
                              void* d_out, int out_size, void* d_ws, size_t ws_size,
                              hipStream_t stream) {
  (void)in_sizes; (void)n_in; (void)out_size; (void)ws_size;
  const float* x   = (const float*)d_in[0];
  const int*   ei  = (const int*)d_in[1];
  const float* ew  = (const float*)d_in[2];
  const float* H0  = (const float*)d_in[3];
  const float* C0  = (const float*)d_in[4];
  const float* W1  = (const float*)d_in[5];
  const float* b1  = (const float*)d_in[6];
  const float* Wi  = (const float*)d_in[7];
  const float* Ti  = (const float*)d_in[8];
  const float* bci = (const float*)d_in[9];
  const float* bii = (const float*)d_in[10];
  const float* Wf  = (const float*)d_in[11];
  const float* Tf  = (const float*)d_in[12];
  const float* bcf = (const float*)d_in[13];
  const float* bif = (const float*)d_in[14];
  const float* Wc  = (const float*)d_in[15];
  const float* Tc  = (const float*)d_in[16];
  const float* bcc = (const float*)d_in[17];
  const float* bic = (const float*)d_in[18];
  const float* Wo  = (const float*)d_in[19];
  const float* To  = (const float*)d_in[20];
  const float* bco = (const float*)d_in[21];
  const float* bio = (const float*)d_in[22];
  const float* Wl  = (const float*)d_in[23];
  const float* bl  = (const float*)d_in[24];

  const int* srcI = ei;
  const int* dstI = ei + EE;

  char* ws = (char*)d_ws;
  size_t off = 0;
  auto carve = [&](size_t bytes) -> char* {
    char* p = ws + off;
    off += (bytes + 255) & ~(size_t)255;
    return p;
  };
  float* dinv          = (float*)carve((size_t)NN * 4);
  int*   cnt           = (int*)carve((size_t)NN * 4);
  int*   loc           = (int*)carve((size_t)NN * 4);
  int*   blkSum        = (int*)carve(512 * 4);
  int*   blkOff        = (int*)carve(512 * 4);
  int*   rowptr        = (int*)carve((size_t)NN * 4);
  int*   cursor        = (int*)carve((size_t)NN * 4);
  int2*  epack         = (int2*)carve((size_t)EE * 8);
  unsigned short* W1T  = (unsigned short*)carve((size_t)FF * FF * 2);
  unsigned short* xwb  = (unsigned short*)carve((size_t)NN * FF * 2);
  unsigned short* A2   = (unsigned short*)carve((size_t)NN * KG * 2);
  unsigned short* BTk  = (unsigned short*)carve((size_t)NCOL * KG * 2);
  float* biasP         = (float*)carve((size_t)NCOL * 4);
  unsigned short* WlT  = (unsigned short*)carve((size_t)CC * SS * 2);
  unsigned short* hrelu = (unsigned short*)carve((size_t)NN * SS * 2);

  float* outSm = (float*)d_out;
  float* HnO = outSm + (size_t)NN * CC;
  float* CnO = HnO + (size_t)NN * SS;

  const int NB = (NN + 255) / 256;  // 391

  k_deg_init<<<NB, 256, 0, stream>>>(dinv, cnt);
  k_deg_acc<<<6250, 256, 0, stream>>>(dstI, ew, dinv, cnt);
  // CSR build (k_scan1 also finalizes dinv)
  k_scan1<<<NB, 256, 0, stream>>>(cnt, loc, blkSum, dinv);
  k_scan2<<<1, 512, 0, stream>>>(blkSum, blkOff, NB);
  k_scan3<<<NB, 256, 0, stream>>>(loc, blkOff, rowptr, cursor);
  k_fill<<<6250, 256, 0, stream>>>(srcI, dstI, ew, dinv, cursor, epack);
  // dense path
  k_pack_w1t<<<64, 256, 0, stream>>>(W1, W1T);
  k_gemm1<<<782, 256, 0, stream>>>(x, W1T, xwb);
  k_gather<<<25000, 256, 0, stream>>>(xwb, epack, rowptr, cnt, dinv, b1, H0, A2);
  k_pack_btk<<<1536, 256, 0, stream>>>(Wi, Wf, Wc, Wo, Ti, Tf, Tc, To, BTk);
  k_pack_bias<<<4, 256, 0, stream>>>(bci, bcf, bcc, bco, bii, bif, bic, bio, biasP);
  k_pack_wlt<<<32, 256, 0, stream>>>(Wl, WlT);
  k_gates<<<6272, 256, 0, stream>>>(A2, BTk, biasP, C0, HnO, CnO, hrelu);
  k_linsoft<<<782, 256, 0, stream>>>(hrelu, WlT, bl, outSm);
}